// Round 9
// baseline (659.580 us; speedup 1.0000x reference)
//
#include <hip/hip_runtime.h>
#include <cmath>

#define NN   50000
#define DIMC 128
#define HC   8
#define HDC  16
#define DC   16
#define WLCAP 400000
#define EPS_A 2e-3f

typedef __bf16 bf16x8 __attribute__((ext_vector_type(8)));
typedef float  f32x4  __attribute__((ext_vector_type(4)));

__device__ __forceinline__ unsigned short f2bf(float f) {
    unsigned int x = __float_as_uint(f);
    unsigned int r = x + 0x7fffu + ((x >> 16) & 1u);
    return (unsigned short)(r >> 16);
}
__device__ __forceinline__ float bf2f(unsigned short u) {
    return __uint_as_float(((unsigned int)u) << 16);
}
__device__ __forceinline__ float blo(unsigned int u) { return __uint_as_float(u << 16); }
__device__ __forceinline__ float bhi(unsigned int u) { return __uint_as_float(u & 0xffff0000u); }
// pack neighbor idx (u16) + weight (fp16) into one u32
__device__ __forceinline__ unsigned int packwi(int r, float w) {
    union { _Float16 f; unsigned short s; } cv; cv.f = (_Float16)w;
    return (unsigned int)(r & 0xffff) | ((unsigned int)cv.s << 16);
}
// pair-granular (16B) XOR swizzle for [R][128] ushort LDS arrays
__device__ __forceinline__ int swz128(int r, int c) {
    return r * 128 + ((((c >> 3) ^ (r & 7)) << 3) | (c & 7));
}
__device__ __forceinline__ bf16x8 ldfrag(const unsigned short* lds, int off_lo, int off_hi) {
    union { uint2 u[2]; bf16x8 v; } t;
    t.u[0] = *(const uint2*)(lds + off_lo);
    t.u[1] = *(const uint2*)(lds + off_hi);
    return t.v;
}

// ---------------- one-time: transpose + bf16-convert FFN weights ----------------
__global__ __launch_bounds__(256) void k_cvtw(const float* __restrict__ W1,
                                              const float* __restrict__ W2,
                                              unsigned short* __restrict__ W1T,   // [512][128]
                                              unsigned short* __restrict__ W2T) { // [128][512]
    int i = blockIdx.x * 256 + threadIdx.x;   // 0..65535
    {
        int c = i >> 7, k = i & 127;
        W1T[i] = f2bf(W1[(size_t)k * 512 + c]);
    }
    {
        int o = i >> 9, c = i & 511;
        W2T[i] = f2bf(W2[(size_t)c * 128 + o]);
    }
}

// ---------------- fused LN1 + 3x GEMM (fp32 vector; reference-accurate) --------
// y=0: fh fp32 + fhb bf16; y=1: ft fp32; y=2: feb bf16
__global__ __launch_bounds__(256) void k_gemm3f(const float* __restrict__ feat,
                                                const float* __restrict__ g1,
                                                const float* __restrict__ b1,
                                                const float* __restrict__ B0,
                                                const float* __restrict__ B1,
                                                const float* __restrict__ B2,
                                                float* __restrict__ fh,
                                                float* __restrict__ ft,
                                                unsigned short* __restrict__ fhb,
                                                unsigned short* __restrict__ feb) {
    __shared__ __align__(16) float xT[128 * 68];   // [k][row], pad 68 keeps 16B align
    __shared__ __align__(16) float Bs[32][128];
    __shared__ float sg1[128], sb1[128];
    int t  = threadIdx.x;
    int r0 = blockIdx.x * 64;

    if (t < 128) { sg1[t] = g1[t]; sb1[t] = b1[t]; }

    // ---- LN1 into xT (transposed) ----
    {
        int row = t >> 2, part = t & 3;
        int gr = r0 + row;
        float vals[32];
        if (gr < NN) {
            const float* fp = feat + (size_t)gr * DIMC + part * 32;
#pragma unroll
            for (int i = 0; i < 8; i++) {
                float4 v = *(const float4*)(fp + i * 4);
                vals[i * 4 + 0] = v.x; vals[i * 4 + 1] = v.y;
                vals[i * 4 + 2] = v.z; vals[i * 4 + 3] = v.w;
            }
        } else {
#pragma unroll
            for (int i = 0; i < 32; i++) vals[i] = 0.0f;
        }
        float s = 0.0f;
#pragma unroll
        for (int i = 0; i < 32; i++) s += vals[i];
        s += __shfl_xor(s, 1); s += __shfl_xor(s, 2);
        float mu = s * (1.0f / 128.0f);
        float sq = 0.0f;
#pragma unroll
        for (int i = 0; i < 32; i++) { float d = vals[i] - mu; sq += d * d; }
        sq += __shfl_xor(sq, 1); sq += __shfl_xor(sq, 2);
        float rstd = 1.0f / sqrtf(sq * (1.0f / 128.0f) + 1e-5f);
        __syncthreads();   // sg1/sb1 ready
#pragma unroll
        for (int i = 0; i < 32; i++) {
            int c = part * 32 + i;
            xT[c * 68 + row] = (vals[i] - mu) * rstd * sg1[c] + sb1[c];
        }
    }
    __syncthreads();

    const float* B = (blockIdx.y == 0) ? B0 : (blockIdx.y == 1 ? B1 : B2);
    int tr = t >> 4;   // rows tr*4
    int tc = t & 15;   // cols tc*8
    float acc[4][8];
#pragma unroll
    for (int i = 0; i < 4; i++)
#pragma unroll
        for (int j = 0; j < 8; j++) acc[i][j] = 0.0f;

    for (int kc = 0; kc < 4; kc++) {
#pragma unroll
        for (int i = 0; i < 16; i++) {             // stage B chunk [32][128]
            int e = t + i * 256;
            int kk = e >> 7, c = e & 127;
            Bs[kk][c] = B[(size_t)(kc * 32 + kk) * DIMC + c];
        }
        __syncthreads();
#pragma unroll 4
        for (int kk = 0; kk < 32; kk++) {
            float4 a  = *(const float4*)&xT[(kc * 32 + kk) * 68 + tr * 4];
            float4 b0 = *(const float4*)&Bs[kk][tc * 8];
            float4 b1v = *(const float4*)&Bs[kk][tc * 8 + 4];
            float av[4] = {a.x, a.y, a.z, a.w};
            float bv[8] = {b0.x, b0.y, b0.z, b0.w, b1v.x, b1v.y, b1v.z, b1v.w};
#pragma unroll
            for (int i = 0; i < 4; i++)
#pragma unroll
                for (int j = 0; j < 8; j++) acc[i][j] = fmaf(av[i], bv[j], acc[i][j]);
        }
        __syncthreads();
    }
#pragma unroll
    for (int i = 0; i < 4; i++) {
        int gr = r0 + tr * 4 + i;
        if (gr < NN) {
            if (blockIdx.y == 0) {
                float4 o0 = {acc[i][0], acc[i][1], acc[i][2], acc[i][3]};
                float4 o1 = {acc[i][4], acc[i][5], acc[i][6], acc[i][7]};
                *(float4*)&fh[(size_t)gr * DIMC + tc * 8]     = o0;
                *(float4*)&fh[(size_t)gr * DIMC + tc * 8 + 4] = o1;
                uint4 pk;
                pk.x = (unsigned int)f2bf(acc[i][0]) | ((unsigned int)f2bf(acc[i][1]) << 16);
                pk.y = (unsigned int)f2bf(acc[i][2]) | ((unsigned int)f2bf(acc[i][3]) << 16);
                pk.z = (unsigned int)f2bf(acc[i][4]) | ((unsigned int)f2bf(acc[i][5]) << 16);
                pk.w = (unsigned int)f2bf(acc[i][6]) | ((unsigned int)f2bf(acc[i][7]) << 16);
                *(uint4*)&fhb[(size_t)gr * DIMC + tc * 8] = pk;
            } else if (blockIdx.y == 1) {
                float4 o0 = {acc[i][0], acc[i][1], acc[i][2], acc[i][3]};
                float4 o1 = {acc[i][4], acc[i][5], acc[i][6], acc[i][7]};
                *(float4*)&ft[(size_t)gr * DIMC + tc * 8]     = o0;
                *(float4*)&ft[(size_t)gr * DIMC + tc * 8 + 4] = o1;
            } else {
                uint4 pk;
                pk.x = (unsigned int)f2bf(acc[i][0]) | ((unsigned int)f2bf(acc[i][1]) << 16);
                pk.y = (unsigned int)f2bf(acc[i][2]) | ((unsigned int)f2bf(acc[i][3]) << 16);
                pk.z = (unsigned int)f2bf(acc[i][4]) | ((unsigned int)f2bf(acc[i][5]) << 16);
                pk.w = (unsigned int)f2bf(acc[i][6]) | ((unsigned int)f2bf(acc[i][7]) << 16);
                *(uint4*)&feb[(size_t)gr * DIMC + tc * 8] = pk;
            }
        }
    }
}

// ---------------- pass 1: bf16 gather, gap-tested top-5 ----------------
__global__ __launch_bounds__(256) void k_score1(const unsigned short* __restrict__ fhb,
                                                const float* __restrict__ ft,
                                                const float* __restrict__ attn,
                                                const int* __restrict__ src,
                                                unsigned int* __restrict__ wi8,
                                                int* __restrict__ wl,
                                                int* __restrict__ cnt) {
    int idx = blockIdx.x * 256 + threadIdx.x;
    if (idx >= NN * HC) return;
    int n = idx >> 3, h = idx & 7;

    float ftv[16], atv[16];
    {
        const float* ftp = ft + ((size_t)n << 7) + h * HDC;
        const float* atp = attn + h * HDC;
#pragma unroll
        for (int q = 0; q < 4; q++) {
            float4 a = *(const float4*)(ftp + q * 4);
            float4 b = *(const float4*)(atp + q * 4);
            ftv[q * 4 + 0] = a.x; ftv[q * 4 + 1] = a.y; ftv[q * 4 + 2] = a.z; ftv[q * 4 + 3] = a.w;
            atv[q * 4 + 0] = b.x; atv[q * 4 + 1] = b.y; atv[q * 4 + 2] = b.z; atv[q * 4 + 3] = b.w;
        }
    }
    const int* sp = src + (size_t)n * DC;
    const float scale = logf(17.0f) / 16.0f;
    float sc[16];
#pragma unroll
    for (int d = 0; d < 16; d++) {
        int r = sp[d];
        const uint4* fp = (const uint4*)(fhb + ((size_t)r << 7) + h * HDC);
        uint4 v0 = fp[0], v1 = fp[1];
        unsigned int uu[8] = {v0.x, v0.y, v0.z, v0.w, v1.x, v1.y, v1.z, v1.w};
        float s = 0.0f;
#pragma unroll
        for (int q = 0; q < 8; q++) {
            float e0 = blo(uu[q]) + ftv[q * 2];
            float e1 = bhi(uu[q]) + ftv[q * 2 + 1];
            e0 = e0 > 0.0f ? e0 : 0.2f * e0;
            e1 = e1 > 0.0f ? e1 : 0.2f * e1;
            s = fmaf(atv[q * 2], e0, s);
            s = fmaf(atv[q * 2 + 1], e1, s);
        }
        sc[d] = s * scale;
    }
    float m = sc[0];
#pragma unroll
    for (int d = 1; d < 16; d++) m = fmaxf(m, sc[d]);
    float p[16]; float sum = 0.0f;
#pragma unroll
    for (int d = 0; d < 16; d++) { p[d] = expf(sc[d] - m); sum += p[d]; }
    float a[16];
#pragma unroll
    for (int d = 0; d < 16; d++) a[d] = p[d] / sum;
    float tmp[16];
#pragma unroll
    for (int d = 0; d < 16; d++) tmp[d] = a[d];
    float thr = 0.0f;
#pragma unroll
    for (int k = 0; k < 5; k++) {
        float vm = tmp[0];
#pragma unroll
        for (int d = 1; d < 16; d++) vm = fmaxf(vm, tmp[d]);
        thr = vm;
        bool rem = false;
#pragma unroll
        for (int d = 0; d < 16; d++) {
            if (!rem && tmp[d] == vm) { tmp[d] = -1.0f; rem = true; }
        }
    }
    float vm6 = tmp[0];
#pragma unroll
    for (int d = 1; d < 16; d++) vm6 = fmaxf(vm6, tmp[d]);

    bool marginal = (thr - vm6) < EPS_A;
    if (marginal) {
        int pos = atomicAdd(cnt, 1);
        if (pos < WLCAP) { wl[pos] = idx; return; }
        // cap overflow fallback (unreachable in practice): finalize from pass1
    }
    float tsum = 0.0f;
#pragma unroll
    for (int d = 0; d < 16; d++) if (a[d] >= thr) tsum += a[d];
    unsigned int slots[8];
    int s = 0;
#pragma unroll
    for (int d = 0; d < 16; d++) {
        if (a[d] >= thr && s < 8) { slots[s] = packwi(sp[d], a[d] / tsum); s++; }
    }
    for (; s < 8; s++) slots[s] = 0;
    size_t base = ((size_t)n * HC + h) * 8;
    uint4 u0 = {slots[0], slots[1], slots[2], slots[3]};
    uint4 u1 = {slots[4], slots[5], slots[6], slots[7]};
    *(uint4*)&wi8[base]     = u0;
    *(uint4*)&wi8[base + 4] = u1;
}

// ---------------- pass 2: exact fp32 recompute for marginal pairs ----------------
__global__ __launch_bounds__(256) void k_fix(const float* __restrict__ fh,
                                             const float* __restrict__ ft,
                                             const float* __restrict__ attn,
                                             const int* __restrict__ src,
                                             const int* __restrict__ wl,
                                             const int* __restrict__ cnt,
                                             unsigned int* __restrict__ wi8) {
    int tid = blockIdx.x * 256 + threadIdx.x;
    if (tid >= *cnt || tid >= WLCAP) return;
    int idx = wl[tid];
    int n = idx >> 3, h = idx & 7;

    float ftv[16], atv[16];
    const float* ftp = ft + ((size_t)n << 7) + h * HDC;
    const float* atp = attn + h * HDC;
#pragma unroll
    for (int q = 0; q < 4; q++) {
        float4 a = *(const float4*)(ftp + q * 4);
        float4 b = *(const float4*)(atp + q * 4);
        ftv[q * 4 + 0] = a.x; ftv[q * 4 + 1] = a.y; ftv[q * 4 + 2] = a.z; ftv[q * 4 + 3] = a.w;
        atv[q * 4 + 0] = b.x; atv[q * 4 + 1] = b.y; atv[q * 4 + 2] = b.z; atv[q * 4 + 3] = b.w;
    }
    const int* sp = src + (size_t)n * DC;
    const float scale = logf(17.0f) / 16.0f;
    float sc[16];
#pragma unroll
    for (int d = 0; d < 16; d++) {
        int r = sp[d];
        const float* fp = fh + ((size_t)r << 7) + h * HDC;
        float s = 0.0f;
#pragma unroll
        for (int q = 0; q < 4; q++) {
            float4 v = *(const float4*)(fp + q * 4);
            float e;
            e = v.x + ftv[q * 4 + 0]; e = e > 0.0f ? e : 0.2f * e; s = fmaf(atv[q * 4 + 0], e, s);
            e = v.y + ftv[q * 4 + 1]; e = e > 0.0f ? e : 0.2f * e; s = fmaf(atv[q * 4 + 1], e, s);
            e = v.z + ftv[q * 4 + 2]; e = e > 0.0f ? e : 0.2f * e; s = fmaf(atv[q * 4 + 2], e, s);
            e = v.w + ftv[q * 4 + 3]; e = e > 0.0f ? e : 0.2f * e; s = fmaf(atv[q * 4 + 3], e, s);
        }
        sc[d] = s * scale;
    }
    float m = sc[0];
#pragma unroll
    for (int d = 1; d < 16; d++) m = fmaxf(m, sc[d]);
    float p[16]; float sum = 0.0f;
#pragma unroll
    for (int d = 0; d < 16; d++) { p[d] = expf(sc[d] - m); sum += p[d]; }
    float a[16];
#pragma unroll
    for (int d = 0; d < 16; d++) a[d] = p[d] / sum;
    float tmp[16];
#pragma unroll
    for (int d = 0; d < 16; d++) tmp[d] = a[d];
    float thr = 0.0f;
#pragma unroll
    for (int k = 0; k < 5; k++) {
        float vm = tmp[0];
#pragma unroll
        for (int d = 1; d < 16; d++) vm = fmaxf(vm, tmp[d]);
        thr = vm;
        bool rem = false;
#pragma unroll
        for (int d = 0; d < 16; d++) {
            if (!rem && tmp[d] == vm) { tmp[d] = -1.0f; rem = true; }
        }
    }
    float tsum = 0.0f;
#pragma unroll
    for (int d = 0; d < 16; d++) if (a[d] >= thr) tsum += a[d];
    unsigned int slots[8];
    int s = 0;
#pragma unroll
    for (int d = 0; d < 16; d++) {
        if (a[d] >= thr && s < 8) { slots[s] = packwi(sp[d], a[d] / tsum); s++; }
    }
    for (; s < 8; s++) slots[s] = 0;
    size_t base = ((size_t)n * HC + h) * 8;
    uint4 u0 = {slots[0], slots[1], slots[2], slots[3]};
    uint4 u1 = {slots[4], slots[5], slots[6], slots[7]};
    *(uint4*)&wi8[base]     = u0;
    *(uint4*)&wi8[base + 4] = u1;
}

// ---------------- one propagation hop (bf16 h, packed weights) ----------------
__global__ __launch_bounds__(256) void k_hop(const unsigned short* __restrict__ hin,
                                             const unsigned short* __restrict__ febf,
                                             const unsigned int* __restrict__ wi8,
                                             unsigned short* __restrict__ hout) {
    __shared__ unsigned int s_wi[256];
    int t  = threadIdx.x;
    int n0 = blockIdx.x * 4;               // 4 nodes / block
    s_wi[t] = wi8[(size_t)n0 * 64 + t];
    __syncthreads();
    int g = t >> 3, lane = t & 7;          // group = (node, head); 8 lanes = 16 feats
    int n = n0 + (g >> 3);
    int h = g & 7;
    const unsigned int* hin32 = (const unsigned int*)hin;
    float a0 = 0.0f, a1 = 0.0f;
    int base = g * 8;
#pragma unroll
    for (int j = 0; j < 8; j++) {
        unsigned int uw = s_wi[base + j];
        if (uw >> 16) {
            union { unsigned short s; _Float16 f; } cv; cv.s = (unsigned short)(uw >> 16);
            float wv = (float)cv.f;
            int r = uw & 0xffff;
            unsigned int u = hin32[(size_t)r * 64 + h * 8 + lane];
            a0 = fmaf(wv, blo(u), a0);
            a1 = fmaf(wv, bhi(u), a1);
        }
    }
    unsigned int fu = ((const unsigned int*)febf)[(size_t)n * 64 + h * 8 + lane];
    a0 = 0.9f * a0 + 0.1f * blo(fu);
    a1 = 0.9f * a1 + 0.1f * bhi(fu);
    ((unsigned int*)hout)[(size_t)n * 64 + h * 8 + lane] =
        (unsigned int)f2bf(a0) | ((unsigned int)f2bf(a1) << 16);
}

// ---------------- rst + LN2 + FFN (bf16 MFMA) + residual ----------------
__global__ __launch_bounds__(256) void k_final(
        const unsigned short* __restrict__ hb,   // h after 5 hops, bf16 [NN][128]
        const float* __restrict__ feat,
        const float* __restrict__ g2,
        const float* __restrict__ b2,
        const unsigned short* __restrict__ W1T,  // [512][128] bf16
        const float* __restrict__ bf1,
        const unsigned short* __restrict__ W2T,  // [128][512] bf16
        const float* __restrict__ bf2,
        float* __restrict__ out) {
    __shared__ unsigned short yrm[64 * 128];   // y bf16 [m][k], swizzled
    __shared__ unsigned short wbuf[128 * 128]; // W1T / W2T chunk, swizzled
    __shared__ unsigned short Trm[64 * 128];   // relu(t) bf16 [m][c], swizzled
    __shared__ float sbf1[512];
    __shared__ float sg2[128];
    __shared__ float sb2[128];
    int t  = threadIdx.x;
    int r0 = blockIdx.x * 64;

    sbf1[t]       = bf1[t];
    sbf1[t + 256] = bf1[t + 256];
    if (t < 128) { sg2[t] = g2[t]; sb2[t] = b2[t]; }
    __syncthreads();

    // ---- rst = bf2f(h)+feat; LN2 -> y bf16 into yrm ----
    {
        int row = t >> 2, part = t & 3;
        int gr = r0 + row;
        float vals[32];
        if (gr < NN) {
            const unsigned short* hp = hb + (size_t)gr * DIMC + part * 32;
            const float* fp = feat + (size_t)gr * DIMC + part * 32;
#pragma unroll
            for (int i = 0; i < 4; i++) {
                uint4 hv = *(const uint4*)(hp + i * 8);
                float4 f0 = *(const float4*)(fp + i * 8);
                float4 f1 = *(const float4*)(fp + i * 8 + 4);
                vals[i*8+0] = blo(hv.x) + f0.x;
                vals[i*8+1] = bhi(hv.x) + f0.y;
                vals[i*8+2] = blo(hv.y) + f0.z;
                vals[i*8+3] = bhi(hv.y) + f0.w;
                vals[i*8+4] = blo(hv.z) + f1.x;
                vals[i*8+5] = bhi(hv.z) + f1.y;
                vals[i*8+6] = blo(hv.w) + f1.z;
                vals[i*8+7] = bhi(hv.w) + f1.w;
            }
        } else {
#pragma unroll
            for (int i = 0; i < 32; i++) vals[i] = 0.0f;
        }
        float s = 0.0f;
#pragma unroll
        for (int i = 0; i < 32; i++) s += vals[i];
        s += __shfl_xor(s, 1); s += __shfl_xor(s, 2);
        float mu = s * (1.0f / 128.0f);
        float sq = 0.0f;
#pragma unroll
        for (int i = 0; i < 32; i++) { float d = vals[i] - mu; sq += d * d; }
        sq += __shfl_xor(sq, 1); sq += __shfl_xor(sq, 2);
        float rstd = 1.0f / sqrtf(sq * (1.0f / 128.0f) + 1e-5f);
#pragma unroll
        for (int pp = 0; pp < 4; pp++) {
            int c = part * 32 + pp * 8;
            unsigned int pk[4];
#pragma unroll
            for (int e = 0; e < 8; e += 2) {
                float y0 = (gr < NN) ? ((vals[pp*8+e]   - mu) * rstd * sg2[c+e]   + sb2[c+e])   : 0.0f;
                float y1 = (gr < NN) ? ((vals[pp*8+e+1] - mu) * rstd * sg2[c+e+1] + sb2[c+e+1]) : 0.0f;
                pk[e >> 1] = (unsigned int)f2bf(y0) | ((unsigned int)f2bf(y1) << 16);
            }
            uint4 v = {pk[0], pk[1], pk[2], pk[3]};
            *(uint4*)&yrm[swz128(row, c)] = v;
        }
    }

    int w  = t >> 6;
    int l  = t & 63;
    int lr = l & 15;
    int lg = l >> 4;
    f32x4 zero4 = {0.0f, 0.0f, 0.0f, 0.0f};
    f32x4 accO[4][2];
#pragma unroll
    for (int mt = 0; mt < 4; mt++)
#pragma unroll
        for (int ot = 0; ot < 2; ot++) accO[mt][ot] = zero4;

    __syncthreads();

    for (int cc = 0; cc < 4; cc++) {
        // stage W1T chunk [128 c][128 k]
#pragma unroll
        for (int i = 0; i < 8; i++) {
            int q = i * 256 + t;
            int c = q >> 4, p = q & 15;
            uint4 v = *(const uint4*)(W1T + (((size_t)(cc * 128 + c)) << 7) + p * 8);
            *(uint4*)&wbuf[swz128(c, p * 8)] = v;
        }
        __syncthreads();

        // phase A: Tt[c][m] = W1cT @ yT   (wave w owns c in [w*32, w*32+32))
        f32x4 tacc[2][4];
#pragma unroll
        for (int ct = 0; ct < 2; ct++)
#pragma unroll
            for (int mt = 0; mt < 4; mt++) tacc[ct][mt] = zero4;
        int cb = w * 32;
#pragma unroll
        for (int kf = 0; kf < 4; kf++) {
            int k0 = kf * 32;
            bf16x8 af[2], bfr[4];
#pragma unroll
            for (int ct = 0; ct < 2; ct++) {
                int c = cb + ct * 16 + lr;
                af[ct] = ldfrag(wbuf, swz128(c, k0 + lg * 4), swz128(c, k0 + 16 + lg * 4));
            }
#pragma unroll
            for (int mt = 0; mt < 4; mt++) {
                int m = mt * 16 + lr;
                bfr[mt] = ldfrag(yrm, swz128(m, k0 + lg * 4), swz128(m, k0 + 16 + lg * 4));
            }
#pragma unroll
            for (int ct = 0; ct < 2; ct++)
#pragma unroll
                for (int mt = 0; mt < 4; mt++)
                    tacc[ct][mt] = __builtin_amdgcn_mfma_f32_16x16x32_bf16(af[ct], bfr[mt], tacc[ct][mt], 0, 0, 0);
        }
        // bias + relu + cvt -> Trm[m][c]
#pragma unroll
        for (int ct = 0; ct < 2; ct++)
#pragma unroll
            for (int mt = 0; mt < 4; mt++) {
                int c0 = cb + ct * 16 + lg * 4;
                int m  = mt * 16 + lr;
                float v0 = fmaxf(tacc[ct][mt][0] + sbf1[cc * 128 + c0 + 0], 0.0f);
                float v1 = fmaxf(tacc[ct][mt][1] + sbf1[cc * 128 + c0 + 1], 0.0f);
                float v2 = fmaxf(tacc[ct][mt][2] + sbf1[cc * 128 + c0 + 2], 0.0f);
                float v3 = fmaxf(tacc[ct][mt][3] + sbf1[cc * 128 + c0 + 3], 0.0f);
                unsigned int lo = (unsigned int)f2bf(v0) | ((unsigned int)f2bf(v1) << 16);
                unsigned int hi = (unsigned int)f2bf(v2) | ((unsigned int)f2bf(v3) << 16);
                uint2 pv = {lo, hi};
                *(uint2*)&Trm[swz128(m, c0)] = pv;
            }
        __syncthreads();
        // stage W2T chunk [128 o][128 c]
#pragma unroll
        for (int i = 0; i < 8; i++) {
            int q = i * 256 + t;
            int o = q >> 4, p = q & 15;
            uint4 v = *(const uint4*)(W2T + ((size_t)o << 9) + cc * 128 + p * 8);
            *(uint4*)&wbuf[swz128(o, p * 8)] = v;
        }
        __syncthreads();
        // phase B: out[m][o] += Trm @ W2cT   (wave w owns o in [w*32, w*32+32))
        int ob = w * 32;
#pragma unroll
        for (int kf = 0; kf < 4; kf++) {
            int k0 = kf * 32;
            bf16x8 aT[4], bw[2];
#pragma unroll
            for (int mt = 0; mt < 4; mt++) {
                int m = mt * 16 + lr;
                aT[mt] = ldfrag(Trm, swz128(m, k0 + lg * 4), swz128(m, k0 + 16 + lg * 4));
            }
#pragma unroll
            for (int ot = 0; ot < 2; ot++) {
                int o = ob + ot * 16 + lr;
                bw[ot] = ldfrag(wbuf, swz128(o, k0 + lg * 4), swz128(o, k0 + 16 + lg * 4));
            }
#pragma unroll
            for (int mt = 0; mt < 4; mt++)
#pragma unroll
                for (int ot = 0; ot < 2; ot++)
                    accO[mt][ot] = __builtin_amdgcn_mfma_f32_16x16x32_bf16(aT[mt], bw[ot], accO[mt][ot], 0, 0, 0);
        }
        __syncthreads();
    }
    // epilogue: + bf2 + rst
    int ob = w * 32;
#pragma unroll
    for (int mt = 0; mt < 4; mt++) {
#pragma unroll
        for (int j = 0; j < 4; j++) {
            int m = mt * 16 + lg * 4 + j;
            int gr = r0 + m;
            if (gr < NN) {
#pragma unroll
                for (int ot = 0; ot < 2; ot++) {
                    int o = ob + ot * 16 + lr;
                    float rst = bf2f(hb[(size_t)gr * DIMC + o]) + feat[(size_t)gr * DIMC + o];
                    out[(size_t)gr * DIMC + o] = accO[mt][ot][j] + bf2[o] + rst;
                }
            }
        }
    }
}

extern "C" void kernel_launch(void* const* d_in, const int* in_sizes, int n_in,
                              void* d_out, int out_size, void* d_ws, size_t ws_size,
                              hipStream_t stream) {
    const float* feat = (const float*)d_in[0];
    const float* Wh   = (const float*)d_in[1];
    const float* Wt   = (const float*)d_in[2];
    const float* We   = (const float*)d_in[3];
    const float* attn = (const float*)d_in[4];
    const float* g1   = (const float*)d_in[5];
    const float* b1   = (const float*)d_in[6];
    const float* g2   = (const float*)d_in[7];
    const float* b2   = (const float*)d_in[8];
    const float* W1   = (const float*)d_in[9];
    const float* bf1  = (const float*)d_in[10];
    const float* W2   = (const float*)d_in[11];
    const float* bf2  = (const float*)d_in[12];
    const int*   src  = (const int*)d_in[13];
    float* out = (float*)d_out;

    size_t NM = (size_t)NN * DIMC;                         // 6.4M elems
    float* fh = (float*)d_ws;                              // [NM] f32 (later hb0/hb1 alias)
    float* ft = fh + NM;                                   // [NM] f32
    unsigned short* fhb = (unsigned short*)(ft + NM);      // [NM] bf16 mirror of fh
    unsigned short* feb = fhb + NM;                        // [NM] bf16 (live through hops)
    unsigned int* wi8 = (unsigned int*)(feb + NM);         // [NN*64] packed (idx|f16 w)
    int* wl  = (int*)(wi8 + (size_t)NN * 64);              // [WLCAP]
    int* cnt = wl + WLCAP;                                 // [1]
    unsigned short* W1T = (unsigned short*)wl;             // overlaps wl (used after k_fix)
    unsigned short* W2T = W1T + 65536;
    unsigned short* hb0 = (unsigned short*)fh;             // alias fh after k_fix
    unsigned short* hb1 = hb0 + NM;

    hipMemsetAsync(cnt, 0, sizeof(int), stream);

    dim3 gg((NN + 63) / 64, 3);
    k_gemm3f<<<gg, 256, 0, stream>>>(feat, g1, b1, Wh, Wt, We, fh, ft, fhb, feb);

    int sgrid = (NN * HC + 255) / 256;
    k_score1<<<sgrid, 256, 0, stream>>>(fhb, ft, attn, src, wi8, wl, cnt);
    k_fix<<<sgrid, 256, 0, stream>>>(fh, ft, attn, src, wl, cnt, wi8);

    k_cvtw<<<256, 256, 0, stream>>>(W1, W2, W1T, W2T);     // overwrites wl region (dead)

    const unsigned short* hin = feb;
    for (int hop = 0; hop < 5; hop++) {
        unsigned short* hout = (hop % 2 == 0) ? hb0 : hb1;
        k_hop<<<NN / 4, 256, 0, stream>>>(hin, feb, wi8, hout);
        hin = hout;
    }
    // final h in hb0
    k_final<<<(NN + 63) / 64, 256, 0, stream>>>(hb0, feat, g2, b2, W1T, bf1, W2T, bf2, out);
}

// Round 10
// 435.967 us; speedup vs baseline: 1.5129x; 1.5129x over previous
//
#include <hip/hip_runtime.h>
#include <cmath>

#define NN   50000
#define NNP  50176          // NN rounded up to 256 (plane stride)
#define DIMC 128
#define HC   8
#define HDC  16
#define DC   16

typedef __bf16 bf16x8 __attribute__((ext_vector_type(8)));
typedef float  f32x4  __attribute__((ext_vector_type(4)));

__device__ __forceinline__ unsigned short f2bf(float f) {
    unsigned int x = __float_as_uint(f);
    unsigned int r = x + 0x7fffu + ((x >> 16) & 1u);
    return (unsigned short)(r >> 16);
}
__device__ __forceinline__ float bf2f(unsigned short u) {
    return __uint_as_float(((unsigned int)u) << 16);
}
__device__ __forceinline__ float blo(unsigned int u) { return __uint_as_float(u << 16); }
__device__ __forceinline__ float bhi(unsigned int u) { return __uint_as_float(u & 0xffff0000u); }
// pack neighbor idx (u16) + weight (fp16) into one u32
__device__ __forceinline__ unsigned int packwi(int r, float w) {
    union { _Float16 f; unsigned short s; } cv; cv.f = (_Float16)w;
    return (unsigned int)(r & 0xffff) | ((unsigned int)cv.s << 16);
}
// pair-granular (16B) XOR swizzle for [R][128] ushort LDS arrays
__device__ __forceinline__ int swz128(int r, int c) {
    return r * 128 + ((((c >> 3) ^ (r & 7)) << 3) | (c & 7));
}
__device__ __forceinline__ bf16x8 ldfrag(const unsigned short* lds, int off_lo, int off_hi) {
    union { uint2 u[2]; bf16x8 v; } t;
    t.u[0] = *(const uint2*)(lds + off_lo);
    t.u[1] = *(const uint2*)(lds + off_hi);
    return t.v;
}

// ---------------- one-time: transpose + bf16-convert FFN weights ----------------
__global__ __launch_bounds__(256) void k_cvtw(const float* __restrict__ W1,
                                              const float* __restrict__ W2,
                                              unsigned short* __restrict__ W1T,   // [512][128]
                                              unsigned short* __restrict__ W2T) { // [128][512]
    int i = blockIdx.x * 256 + threadIdx.x;   // 0..65535
    {
        int c = i >> 7, k = i & 127;
        W1T[i] = f2bf(W1[(size_t)k * 512 + c]);
    }
    {
        int o = i >> 9, c = i & 511;
        W2T[i] = f2bf(W2[(size_t)c * 128 + o]);
    }
}

// ---------------- fused LN1 + 3x GEMM (fp32 vector; reference-accurate) --------
// outputs per-head PLANES: y=0 -> fhp fp32 [8][NNP][16]; y=1 -> ftp fp32; y=2 -> febp bf16
__global__ __launch_bounds__(256) void k_gemm3f(const float* __restrict__ feat,
                                                const float* __restrict__ g1,
                                                const float* __restrict__ b1,
                                                const float* __restrict__ B0,
                                                const float* __restrict__ B1,
                                                const float* __restrict__ B2,
                                                float* __restrict__ fhp,
                                                float* __restrict__ ftp,
                                                unsigned short* __restrict__ febp) {
    __shared__ __align__(16) float xT[128 * 68];   // [k][row], pad 68 keeps 16B align
    __shared__ __align__(16) float Bs[32][128];
    __shared__ float sg1[128], sb1[128];
    int t  = threadIdx.x;
    int r0 = blockIdx.x * 64;

    if (t < 128) { sg1[t] = g1[t]; sb1[t] = b1[t]; }

    // ---- LN1 into xT (transposed) ----
    {
        int row = t >> 2, part = t & 3;
        int gr = r0 + row;
        float vals[32];
        if (gr < NN) {
            const float* fp = feat + (size_t)gr * DIMC + part * 32;
#pragma unroll
            for (int i = 0; i < 8; i++) {
                float4 v = *(const float4*)(fp + i * 4);
                vals[i * 4 + 0] = v.x; vals[i * 4 + 1] = v.y;
                vals[i * 4 + 2] = v.z; vals[i * 4 + 3] = v.w;
            }
        } else {
#pragma unroll
            for (int i = 0; i < 32; i++) vals[i] = 0.0f;
        }
        float s = 0.0f;
#pragma unroll
        for (int i = 0; i < 32; i++) s += vals[i];
        s += __shfl_xor(s, 1); s += __shfl_xor(s, 2);
        float mu = s * (1.0f / 128.0f);
        float sq = 0.0f;
#pragma unroll
        for (int i = 0; i < 32; i++) { float d = vals[i] - mu; sq += d * d; }
        sq += __shfl_xor(sq, 1); sq += __shfl_xor(sq, 2);
        float rstd = 1.0f / sqrtf(sq * (1.0f / 128.0f) + 1e-5f);
        __syncthreads();   // sg1/sb1 ready
#pragma unroll
        for (int i = 0; i < 32; i++) {
            int c = part * 32 + i;
            xT[c * 68 + row] = (vals[i] - mu) * rstd * sg1[c] + sb1[c];
        }
    }
    __syncthreads();

    const float* B = (blockIdx.y == 0) ? B0 : (blockIdx.y == 1 ? B1 : B2);
    int tr = t >> 4;   // rows tr*4
    int tc = t & 15;   // cols tc*8
    float acc[4][8];
#pragma unroll
    for (int i = 0; i < 4; i++)
#pragma unroll
        for (int j = 0; j < 8; j++) acc[i][j] = 0.0f;

    for (int kc = 0; kc < 4; kc++) {
#pragma unroll
        for (int i = 0; i < 16; i++) {             // stage B chunk [32][128]
            int e = t + i * 256;
            int kk = e >> 7, c = e & 127;
            Bs[kk][c] = B[(size_t)(kc * 32 + kk) * DIMC + c];
        }
        __syncthreads();
#pragma unroll 4
        for (int kk = 0; kk < 32; kk++) {
            float4 a  = *(const float4*)&xT[(kc * 32 + kk) * 68 + tr * 4];
            float4 b0 = *(const float4*)&Bs[kk][tc * 8];
            float4 b1v = *(const float4*)&Bs[kk][tc * 8 + 4];
            float av[4] = {a.x, a.y, a.z, a.w};
            float bv[8] = {b0.x, b0.y, b0.z, b0.w, b1v.x, b1v.y, b1v.z, b1v.w};
#pragma unroll
            for (int i = 0; i < 4; i++)
#pragma unroll
                for (int j = 0; j < 8; j++) acc[i][j] = fmaf(av[i], bv[j], acc[i][j]);
        }
        __syncthreads();
    }
    // epilogue: write planes. cols tc*8.. -> head h = tc>>1, feat f = (tc&1)*8
    int h = tc >> 1, f = (tc & 1) * 8;
#pragma unroll
    for (int i = 0; i < 4; i++) {
        int gr = r0 + tr * 4 + i;
        if (gr < NN) {
            size_t po = ((size_t)h * NNP + gr) * 16 + f;
            if (blockIdx.y == 0) {
                float4 o0 = {acc[i][0], acc[i][1], acc[i][2], acc[i][3]};
                float4 o1 = {acc[i][4], acc[i][5], acc[i][6], acc[i][7]};
                *(float4*)&fhp[po]     = o0;
                *(float4*)&fhp[po + 4] = o1;
            } else if (blockIdx.y == 1) {
                float4 o0 = {acc[i][0], acc[i][1], acc[i][2], acc[i][3]};
                float4 o1 = {acc[i][4], acc[i][5], acc[i][6], acc[i][7]};
                *(float4*)&ftp[po]     = o0;
                *(float4*)&ftp[po + 4] = o1;
            } else {
                uint4 pk;
                pk.x = (unsigned int)f2bf(acc[i][0]) | ((unsigned int)f2bf(acc[i][1]) << 16);
                pk.y = (unsigned int)f2bf(acc[i][2]) | ((unsigned int)f2bf(acc[i][3]) << 16);
                pk.z = (unsigned int)f2bf(acc[i][4]) | ((unsigned int)f2bf(acc[i][5]) << 16);
                pk.w = (unsigned int)f2bf(acc[i][6]) | ((unsigned int)f2bf(acc[i][7]) << 16);
                *(uint4*)&((unsigned int*)febp)[po >> 1] = pk;
            }
        }
    }
}

// ---------------- exact fp32 scores, single pass, head-plane partitioned ----------
// blockIdx & 7 = head -> XCD pinning; per-XCD working set = one 3.2MB fh plane (L2-fit)
__global__ __launch_bounds__(256) void k_score(const float* __restrict__ fhp,
                                               const float* __restrict__ ftp,
                                               const float* __restrict__ attn,
                                               const int* __restrict__ src,
                                               unsigned int* __restrict__ wi8p) {
    int h = blockIdx.x & 7;
    int n = (blockIdx.x >> 3) * 256 + threadIdx.x;
    if (n >= NN) return;

    float atv[16], ftv[16];
    {
        const float* ap = attn + h * HDC;
        const float* fp0 = ftp + ((size_t)h * NNP + n) * 16;
#pragma unroll
        for (int q = 0; q < 4; q++) {
            float4 b = *(const float4*)(ap + q * 4);
            float4 a = *(const float4*)(fp0 + q * 4);
            atv[q * 4 + 0] = b.x; atv[q * 4 + 1] = b.y; atv[q * 4 + 2] = b.z; atv[q * 4 + 3] = b.w;
            ftv[q * 4 + 0] = a.x; ftv[q * 4 + 1] = a.y; ftv[q * 4 + 2] = a.z; ftv[q * 4 + 3] = a.w;
        }
    }
    const int* sp = src + (size_t)n * DC;
    const float scale = logf(17.0f) / 16.0f;   // log(D+1)/HD
    float sc[16];
#pragma unroll
    for (int d = 0; d < 16; d++) {
        int r = sp[d];
        const float* fp = fhp + ((size_t)h * NNP + r) * 16;
        float s = 0.0f;
#pragma unroll
        for (int q = 0; q < 4; q++) {
            float4 v = *(const float4*)(fp + q * 4);
            float e;
            e = v.x + ftv[q * 4 + 0]; e = e > 0.0f ? e : 0.2f * e; s = fmaf(atv[q * 4 + 0], e, s);
            e = v.y + ftv[q * 4 + 1]; e = e > 0.0f ? e : 0.2f * e; s = fmaf(atv[q * 4 + 1], e, s);
            e = v.z + ftv[q * 4 + 2]; e = e > 0.0f ? e : 0.2f * e; s = fmaf(atv[q * 4 + 2], e, s);
            e = v.w + ftv[q * 4 + 3]; e = e > 0.0f ? e : 0.2f * e; s = fmaf(atv[q * 4 + 3], e, s);
        }
        sc[d] = s * scale;
    }
    float m = sc[0];
#pragma unroll
    for (int d = 1; d < 16; d++) m = fmaxf(m, sc[d]);
    float p[16]; float sum = 0.0f;
#pragma unroll
    for (int d = 0; d < 16; d++) { p[d] = expf(sc[d] - m); sum += p[d]; }
    float a[16];
#pragma unroll
    for (int d = 0; d < 16; d++) a[d] = p[d] / sum;
    // 5th-largest (counting multiplicity) — matches jnp.top_k semantics
    float tmp[16];
#pragma unroll
    for (int d = 0; d < 16; d++) tmp[d] = a[d];
    float thr = 0.0f;
#pragma unroll
    for (int k = 0; k < 5; k++) {
        float vm = tmp[0];
#pragma unroll
        for (int d = 1; d < 16; d++) vm = fmaxf(vm, tmp[d]);
        thr = vm;
        bool rem = false;
#pragma unroll
        for (int d = 0; d < 16; d++) {
            if (!rem && tmp[d] == vm) { tmp[d] = -1.0f; rem = true; }
        }
    }
    float tsum = 0.0f;
#pragma unroll
    for (int d = 0; d < 16; d++) if (a[d] >= thr) tsum += a[d];
    unsigned int slots[8];
    int s = 0;
#pragma unroll
    for (int d = 0; d < 16; d++) {
        if (a[d] >= thr && s < 8) { slots[s] = packwi(sp[d], a[d] / tsum); s++; }
    }
    for (; s < 8; s++) slots[s] = 0;
    size_t base = ((size_t)h * NNP + n) * 8;
    uint4 u0 = {slots[0], slots[1], slots[2], slots[3]};
    uint4 u1 = {slots[4], slots[5], slots[6], slots[7]};
    *(uint4*)&wi8p[base]     = u0;
    *(uint4*)&wi8p[base + 4] = u1;
}

// ---------------- one propagation hop (bf16 planes, XCD-pinned by head) ----------
__global__ __launch_bounds__(256) void k_hop(const unsigned short* __restrict__ hinp,
                                             const unsigned short* __restrict__ febp,
                                             const unsigned int* __restrict__ wi8p,
                                             unsigned short* __restrict__ houtp) {
    __shared__ unsigned int s_wi[1024];    // 128 nodes x 8 slots
    int t  = threadIdx.x;
    int h  = blockIdx.x & 7;
    int n0 = (blockIdx.x >> 3) * 128;
    *(uint4*)&s_wi[t * 4] = *(const uint4*)&wi8p[((size_t)h * NNP + n0) * 8 + t * 4];
    __syncthreads();
    int nn = t >> 1, half = t & 1;         // 2 lanes per node: 16B each
    int n = n0 + nn;
    if (n >= NN) return;
    const unsigned int* hin32 = (const unsigned int*)hinp;
    float acc[8];
#pragma unroll
    for (int i = 0; i < 8; i++) acc[i] = 0.0f;
    int base = nn * 8;
#pragma unroll
    for (int j = 0; j < 8; j++) {
        unsigned int uw = s_wi[base + j];
        if (uw >> 16) {
            union { unsigned short s; _Float16 f; } cv; cv.s = (unsigned short)(uw >> 16);
            float wv = (float)cv.f;
            int r = uw & 0xffff;
            uint4 u = *(const uint4*)&hin32[((size_t)h * NNP + r) * 8 + half * 4];
            acc[0] = fmaf(wv, blo(u.x), acc[0]); acc[1] = fmaf(wv, bhi(u.x), acc[1]);
            acc[2] = fmaf(wv, blo(u.y), acc[2]); acc[3] = fmaf(wv, bhi(u.y), acc[3]);
            acc[4] = fmaf(wv, blo(u.z), acc[4]); acc[5] = fmaf(wv, bhi(u.z), acc[5]);
            acc[6] = fmaf(wv, blo(u.w), acc[6]); acc[7] = fmaf(wv, bhi(u.w), acc[7]);
        }
    }
    uint4 fu = *(const uint4*)&((const unsigned int*)febp)[((size_t)h * NNP + n) * 8 + half * 4];
    float fv[8] = {blo(fu.x), bhi(fu.x), blo(fu.y), bhi(fu.y),
                   blo(fu.z), bhi(fu.z), blo(fu.w), bhi(fu.w)};
    uint4 o;
    o.x = (unsigned int)f2bf(0.9f * acc[0] + 0.1f * fv[0]) | ((unsigned int)f2bf(0.9f * acc[1] + 0.1f * fv[1]) << 16);
    o.y = (unsigned int)f2bf(0.9f * acc[2] + 0.1f * fv[2]) | ((unsigned int)f2bf(0.9f * acc[3] + 0.1f * fv[3]) << 16);
    o.z = (unsigned int)f2bf(0.9f * acc[4] + 0.1f * fv[4]) | ((unsigned int)f2bf(0.9f * acc[5] + 0.1f * fv[5]) << 16);
    o.w = (unsigned int)f2bf(0.9f * acc[6] + 0.1f * fv[6]) | ((unsigned int)f2bf(0.9f * acc[7] + 0.1f * fv[7]) << 16);
    *(uint4*)&((unsigned int*)houtp)[((size_t)h * NNP + n) * 8 + half * 4] = o;
}

// ---------------- rst + LN2 + FFN (bf16 MFMA) + residual (reads head planes) ----
__global__ __launch_bounds__(256) void k_final(
        const unsigned short* __restrict__ hbp,  // h planes [8][NNP][16] bf16
        const float* __restrict__ feat,
        const float* __restrict__ g2,
        const float* __restrict__ b2,
        const unsigned short* __restrict__ W1T,  // [512][128] bf16
        const float* __restrict__ bf1,
        const unsigned short* __restrict__ W2T,  // [128][512] bf16
        const float* __restrict__ bf2,
        float* __restrict__ out) {
    __shared__ unsigned short yrm[64 * 128];   // y bf16 [m][k], swizzled
    __shared__ unsigned short wbuf[128 * 128]; // W1T / W2T chunk, swizzled
    __shared__ unsigned short Trm[64 * 128];   // relu(t) bf16 [m][c], swizzled
    __shared__ float sbf1[512];
    __shared__ float sg2[128];
    __shared__ float sb2[128];
    int t  = threadIdx.x;
    int r0 = blockIdx.x * 64;

    sbf1[t]       = bf1[t];
    sbf1[t + 256] = bf1[t + 256];
    if (t < 128) { sg2[t] = g2[t]; sb2[t] = b2[t]; }
    __syncthreads();

    // ---- rst = bf2f(h)+feat; LN2 -> y bf16 into yrm ----
    {
        int row = t >> 2, part = t & 3;
        int gr = r0 + row;
        float vals[32];
        if (gr < NN) {
            const float* fp = feat + (size_t)gr * DIMC + part * 32;
#pragma unroll
            for (int pl = 0; pl < 2; pl++) {
                int p = part * 2 + pl;
                const unsigned int* hp32 = (const unsigned int*)hbp + ((size_t)p * NNP + gr) * 8;
                uint4 u0 = *(const uint4*)hp32;
                uint4 u1 = *(const uint4*)(hp32 + 4);
                float4 f0 = *(const float4*)(fp + pl * 16);
                float4 f1 = *(const float4*)(fp + pl * 16 + 4);
                float4 f2v = *(const float4*)(fp + pl * 16 + 8);
                float4 f3 = *(const float4*)(fp + pl * 16 + 12);
                int b = pl * 16;
                vals[b + 0]  = blo(u0.x) + f0.x;  vals[b + 1]  = bhi(u0.x) + f0.y;
                vals[b + 2]  = blo(u0.y) + f0.z;  vals[b + 3]  = bhi(u0.y) + f0.w;
                vals[b + 4]  = blo(u0.z) + f1.x;  vals[b + 5]  = bhi(u0.z) + f1.y;
                vals[b + 6]  = blo(u0.w) + f1.z;  vals[b + 7]  = bhi(u0.w) + f1.w;
                vals[b + 8]  = blo(u1.x) + f2v.x; vals[b + 9]  = bhi(u1.x) + f2v.y;
                vals[b + 10] = blo(u1.y) + f2v.z; vals[b + 11] = bhi(u1.y) + f2v.w;
                vals[b + 12] = blo(u1.z) + f3.x;  vals[b + 13] = bhi(u1.z) + f3.y;
                vals[b + 14] = blo(u1.w) + f3.z;  vals[b + 15] = bhi(u1.w) + f3.w;
            }
        } else {
#pragma unroll
            for (int i = 0; i < 32; i++) vals[i] = 0.0f;
        }
        float s = 0.0f;
#pragma unroll
        for (int i = 0; i < 32; i++) s += vals[i];
        s += __shfl_xor(s, 1); s += __shfl_xor(s, 2);
        float mu = s * (1.0f / 128.0f);
        float sq = 0.0f;
#pragma unroll
        for (int i = 0; i < 32; i++) { float d = vals[i] - mu; sq += d * d; }
        sq += __shfl_xor(sq, 1); sq += __shfl_xor(sq, 2);
        float rstd = 1.0f / sqrtf(sq * (1.0f / 128.0f) + 1e-5f);
#pragma unroll
        for (int pp = 0; pp < 4; pp++) {
            int c = part * 32 + pp * 8;
            unsigned int pk[4];
#pragma unroll
            for (int e = 0; e < 8; e += 2) {
                float y0 = (gr < NN) ? ((vals[pp*8+e]   - mu) * rstd * sg2[c+e]   + sb2[c+e])   : 0.0f;
                float y1 = (gr < NN) ? ((vals[pp*8+e+1] - mu) * rstd * sg2[c+e+1] + sb2[c+e+1]) : 0.0f;
                pk[e >> 1] = (unsigned int)f2bf(y0) | ((unsigned int)f2bf(y1) << 16);
            }
            uint4 v = {pk[0], pk[1], pk[2], pk[3]};
            *(uint4*)&yrm[swz128(row, c)] = v;
        }
    }

    int w  = t >> 6;
    int l  = t & 63;
    int lr = l & 15;
    int lg = l >> 4;
    f32x4 zero4 = {0.0f, 0.0f, 0.0f, 0.0f};
    f32x4 accO[4][2];
#pragma unroll
    for (int mt = 0; mt < 4; mt++)
#pragma unroll
        for (int ot = 0; ot < 2; ot++) accO[mt][ot] = zero4;

    __syncthreads();

    for (int cc = 0; cc < 4; cc++) {
        // stage W1T chunk [128 c][128 k]
#pragma unroll
        for (int i = 0; i < 8; i++) {
            int q = i * 256 + t;
            int c = q >> 4, p = q & 15;
            uint4 v = *(const uint4*)(W1T + (((size_t)(cc * 128 + c)) << 7) + p * 8);
            *(uint4*)&wbuf[swz128(c, p * 8)] = v;
        }
        __syncthreads();

        // phase A: Tt[c][m] = W1cT @ yT   (wave w owns c in [w*32, w*32+32))
        f32x4 tacc[2][4];
#pragma unroll
        for (int ct = 0; ct < 2; ct++)
#pragma unroll
            for (int mt = 0; mt < 4; mt++) tacc[ct][mt] = zero4;
        int cb = w * 32;
#pragma unroll
        for (int kf = 0; kf < 4; kf++) {
            int k0 = kf * 32;
            bf16x8 af[2], bfr[4];
#pragma unroll
            for (int ct = 0; ct < 2; ct++) {
                int c = cb + ct * 16 + lr;
                af[ct] = ldfrag(wbuf, swz128(c, k0 + lg * 4), swz128(c, k0 + 16 + lg * 4));
            }
#pragma unroll
            for (int mt = 0; mt < 4; mt++) {
                int m = mt * 16 + lr;
                bfr[mt] = ldfrag(yrm, swz128(m, k0 + lg * 4), swz128(m, k0 + 16 + lg * 4));
            }
#pragma unroll
            for (int ct = 0; ct < 2; ct++)
#pragma unroll
                for (int mt = 0; mt < 4; mt++)
                    tacc[ct][mt] = __builtin_amdgcn_mfma_f32_16x16x32_bf16(af[ct], bfr[mt], tacc[ct][mt], 0, 0, 0);
        }
        // bias + relu + cvt -> Trm[m][c]
#pragma unroll
        for (int ct = 0; ct < 2; ct++)
#pragma unroll
            for (int mt = 0; mt < 4; mt++) {
                int c0 = cb + ct * 16 + lg * 4;
                int m  = mt * 16 + lr;
                float v0 = fmaxf(tacc[ct][mt][0] + sbf1[cc * 128 + c0 + 0], 0.0f);
                float v1 = fmaxf(tacc[ct][mt][1] + sbf1[cc * 128 + c0 + 1], 0.0f);
                float v2 = fmaxf(tacc[ct][mt][2] + sbf1[cc * 128 + c0 + 2], 0.0f);
                float v3 = fmaxf(tacc[ct][mt][3] + sbf1[cc * 128 + c0 + 3], 0.0f);
                unsigned int lo = (unsigned int)f2bf(v0) | ((unsigned int)f2bf(v1) << 16);
                unsigned int hi = (unsigned int)f2bf(v2) | ((unsigned int)f2bf(v3) << 16);
                uint2 pv = {lo, hi};
                *(uint2*)&Trm[swz128(m, c0)] = pv;
            }
        __syncthreads();
        // stage W2T chunk [128 o][128 c]
#pragma unroll
        for (int i = 0; i < 8; i++) {
            int q = i * 256 + t;
            int o = q >> 4, p = q & 15;
            uint4 v = *(const uint4*)(W2T + ((size_t)o << 9) + cc * 128 + p * 8);
            *(uint4*)&wbuf[swz128(o, p * 8)] = v;
        }
        __syncthreads();
        // phase B: out[m][o] += Trm @ W2cT   (wave w owns o in [w*32, w*32+32))
        int ob = w * 32;
#pragma unroll
        for (int kf = 0; kf < 4; kf++) {
            int k0 = kf * 32;
            bf16x8 aT[4], bw[2];
#pragma unroll
            for (int mt = 0; mt < 4; mt++) {
                int m = mt * 16 + lr;
                aT[mt] = ldfrag(Trm, swz128(m, k0 + lg * 4), swz128(m, k0 + 16 + lg * 4));
            }
#pragma unroll
            for (int ot = 0; ot < 2; ot++) {
                int o = ob + ot * 16 + lr;
                bw[ot] = ldfrag(wbuf, swz128(o, k0 + lg * 4), swz128(o, k0 + 16 + lg * 4));
            }
#pragma unroll
            for (int mt = 0; mt < 4; mt++)
#pragma unroll
                for (int ot = 0; ot < 2; ot++)
                    accO[mt][ot] = __builtin_amdgcn_mfma_f32_16x16x32_bf16(aT[mt], bw[ot], accO[mt][ot], 0, 0, 0);
        }
        __syncthreads();
    }
    // epilogue: + bf2 + rst (hb read from planes; o's plane = w*2+ot, feat idx = lr)
    int ob = w * 32;
#pragma unroll
    for (int mt = 0; mt < 4; mt++) {
#pragma unroll
        for (int j = 0; j < 4; j++) {
            int m = mt * 16 + lg * 4 + j;
            int gr = r0 + m;
            if (gr < NN) {
#pragma unroll
                for (int ot = 0; ot < 2; ot++) {
                    int o = ob + ot * 16 + lr;
                    int q = w * 2 + ot;
                    float hv = bf2f(hbp[((size_t)q * NNP + gr) * 16 + lr]);
                    float rst = hv + feat[(size_t)gr * DIMC + o];
                    out[(size_t)gr * DIMC + o] = accO[mt][ot][j] + bf2[o] + rst;
                }
            }
        }
    }
}

extern "C" void kernel_launch(void* const* d_in, const int* in_sizes, int n_in,
                              void* d_out, int out_size, void* d_ws, size_t ws_size,
                              hipStream_t stream) {
    const float* feat = (const float*)d_in[0];
    const float* Wh   = (const float*)d_in[1];
    const float* Wt   = (const float*)d_in[2];
    const float* We   = (const float*)d_in[3];
    const float* attn = (const float*)d_in[4];
    const float* g1   = (const float*)d_in[5];
    const float* b1   = (const float*)d_in[6];
    const float* g2   = (const float*)d_in[7];
    const float* b2   = (const float*)d_in[8];
    const float* W1   = (const float*)d_in[9];
    const float* bf1  = (const float*)d_in[10];
    const float* W2   = (const float*)d_in[11];
    const float* bf2  = (const float*)d_in[12];
    const int*   src  = (const int*)d_in[13];
    float* out = (float*)d_out;

    size_t PL = (size_t)NNP * 16;                          // elems per plane
    float* fhp = (float*)d_ws;                             // [8][NNP][16] f32 (25.7MB; later hbp0)
    float* ftp = fhp + 8 * PL;                             // [8][NNP][16] f32 (later hbp1)
    unsigned short* febp = (unsigned short*)(ftp + 8 * PL);// [8][NNP][16] bf16
    unsigned int* wi8p = (unsigned int*)(febp + 8 * PL);   // [8][NNP][8] packed (idx|f16 w)
    unsigned short* W1T = (unsigned short*)(wi8p + (size_t)8 * NNP * 8);
    unsigned short* W2T = W1T + 65536;
    unsigned short* hbp0 = (unsigned short*)fhp;           // alias fhp after k_score
    unsigned short* hbp1 = (unsigned short*)ftp;           // alias ftp after k_score

    k_cvtw<<<256, 256, 0, stream>>>(W1, W2, W1T, W2T);

    dim3 gg((NN + 63) / 64, 3);
    k_gemm3f<<<gg, 256, 0, stream>>>(feat, g1, b1, Wh, Wt, We, fhp, ftp, febp);

    // 8 heads x 196 n-chunks; blockIdx&7 = head -> XCD pinning under %8 round-robin
    k_score<<<8 * ((NN + 255) / 256), 256, 0, stream>>>(fhp, ftp, attn, src, wi8p);

    const unsigned short* hin = febp;
    int hgrid = 8 * ((NN + 127) / 128);
    for (int hop = 0; hop < 5; hop++) {
        unsigned short* hout = (hop % 2 == 0) ? hbp0 : hbp1;
        k_hop<<<hgrid, 256, 0, stream>>>(hin, febp, wi8p, hout);
        hin = hout;
    }
    // final h in hbp0
    k_final<<<(NN + 63) / 64, 256, 0, stream>>>(hbp0, feat, g2, b2, W1T, bf1, W2T, bf2, out);
}